// Round 7
// baseline (3438.919 us; speedup 1.0000x reference)
//
#include <hip/hip_runtime.h>
#include <hip/hip_bf16.h>
#include <stdint.h>

#define IN_F   4096
#define OUT_F  11008
#define M_DIM  8192          // B*S

// ---------------- 8-phase 256x256 geometry, int8 ----------------
#define BM 256
#define BN 256
#define BK 64                  // 64 i8 elems = 64 B per row per K-tile
#define TM (M_DIM / BM)        // 32
#define TN (OUT_F / BN)        // 43
#define NWG (TM * TN)          // 1376
#define KT (IN_F / BK)         // 64 K-tiles
#define KC (IN_F / 16)         // 256 16-B chunks per row
#define HTB (128 * 64)         // half-tile bytes (128 rows x 64 B) = 8 KiB

typedef __attribute__((ext_vector_type(4))) int   int32x4;
typedef __attribute__((ext_vector_type(8))) short short8;
typedef __attribute__((ext_vector_type(4))) float f32x4;

union Pack8 { __bf16 h[8]; uint4 u; };
union PackI { char c[16]; ::int4 v; };

__device__ inline uint4 pack8_f(float4 f0, float4 f1) {
    Pack8 o;
    o.h[0] = (__bf16)f0.x; o.h[1] = (__bf16)f0.y;
    o.h[2] = (__bf16)f0.z; o.h[3] = (__bf16)f0.w;
    o.h[4] = (__bf16)f1.x; o.h[5] = (__bf16)f1.y;
    o.h[6] = (__bf16)f1.z; o.h[7] = (__bf16)f1.w;
    return o.u;
}

__device__ inline uint4 dequant8(int4 v, float s, float zb) {
    Pack8 o;
    int pv[4] = {v.x, v.y, v.z, v.w};
#pragma unroll
    for (int j = 0; j < 4; ++j) {
        o.h[2 * j]     = (__bf16)fmaf((float)(pv[j] & 15), s, zb);
        o.h[2 * j + 1] = (__bf16)fmaf((float)((pv[j] >> 4) & 15), s, zb);
    }
    return o.u;
}

#define GLOAD_LDS16(g, l)                                                     \
    __builtin_amdgcn_global_load_lds(                                         \
        (const __attribute__((address_space(1))) void*)(g),                   \
        (__attribute__((address_space(3))) void*)(l), 16, 0, 0)

#define BAR()   __builtin_amdgcn_s_barrier()
#define SBAR0() __builtin_amdgcn_sched_barrier(0)
#define VMW(n)  asm volatile("s_waitcnt vmcnt(" #n ")" ::: "memory")

// ---------- preprocessing: x fp32 -> i8 with per-row absmax scale ----------
__global__ __launch_bounds__(256) void quant_x_kernel(const float* __restrict__ x,
        char* __restrict__ xq, float* __restrict__ srow) {
    const int row = blockIdx.x;
    const int t   = threadIdx.x;
    const float4* xr = (const float4*)(x + (size_t)row * IN_F) + t * 4;
    float4 v[4];
    float am = 0.f;
#pragma unroll
    for (int j = 0; j < 4; ++j) {
        v[j] = xr[j];
        am = fmaxf(am, fmaxf(fmaxf(fabsf(v[j].x), fabsf(v[j].y)),
                             fmaxf(fabsf(v[j].z), fabsf(v[j].w))));
    }
#pragma unroll
    for (int off = 32; off; off >>= 1) am = fmaxf(am, __shfl_xor(am, off, 64));
    __shared__ float wm4[4];
    if ((t & 63) == 0) wm4[t >> 6] = am;
    __syncthreads();
    am = fmaxf(fmaxf(wm4[0], wm4[1]), fmaxf(wm4[2], wm4[3]));
    const float qs = am > 0.f ? 127.f / am : 0.f;
    if (t == 0) srow[row] = am > 0.f ? am * (1.f / 127.f) : 0.f;
    PackI o;
#pragma unroll
    for (int j = 0; j < 4; ++j) {
        const float* f = (const float*)&v[j];
#pragma unroll
        for (int e = 0; e < 4; ++e) {
            float q = rintf(f[e] * qs);
            q = fminf(127.f, fmaxf(-127.f, q));
            o.c[j * 4 + e] = (char)(int)q;
        }
    }
    ((::int4*)(xq + (size_t)row * IN_F))[t] = o.v;
}

// ---------- preprocessing: packed int4 W -> i8 (q - zp, EXACT) ----------
__global__ void deqw_i8_kernel(const int* __restrict__ pw, const int* __restrict__ zps,
                               char* __restrict__ wq, int nChunks) {
    int stride = gridDim.x * blockDim.x;
    for (int c = blockIdx.x * blockDim.x + threadIdx.x; c < nChunks; c += stride) {
        int row = c >> 8;          // 256 16-B chunks per row
        int cc  = c & 255;
        int zp  = zps[row];
        const ::int4* p = (const ::int4*)(pw + (size_t)row * (IN_F / 2) + cc * 8);
        ::int4 v0 = p[0], v1 = p[1];
        int pv[8] = {v0.x, v0.y, v0.z, v0.w, v1.x, v1.y, v1.z, v1.w};
        PackI o;
#pragma unroll
        for (int j = 0; j < 8; ++j) {
            o.c[2 * j]     = (char)((pv[j] & 15) - zp);
            o.c[2 * j + 1] = (char)(((pv[j] >> 4) & 15) - zp);
        }
        ((::int4*)wq)[c] = o.v;
    }
}

// ---------- 8-phase helpers (i8: 1 gload_lds per wave per half-tile) ----------
// LDS half-tile: [128 rows][64 B], slot swizzle: 16-B slot s of row r holds
// global chunk s ^ (r&3). gload_lds writes linearly (lane l -> row wid*16 + l>>2,
// slot l&3), so the source chunk is pre-swizzled: (l&3) ^ ((l>>2)&3).
__device__ inline void stA(char* smem, const uint4* gA, int t, int h, int buf, int wo) {
    GLOAD_LDS16(gA + (size_t)h * 64 * KC + (t & (KT - 1)) * 4,
                smem + ((buf * 2 + 0) * 2 + h) * HTB + wo);
}
__device__ inline void stB(char* smem, const uint4* gB, int t, int h, int buf, int wo) {
    GLOAD_LDS16(gB + (size_t)h * 32 * KC + (t & (KT - 1)) * 4,
                smem + ((buf * 2 + 1) * 2 + h) * HTB + wo);
}

template <int QM>
__device__ inline void read_A(const char* smem, int buf, int wm, int lane, int32x4 (&a)[4]) {
    const char* base = smem + ((buf * 2 + 0) * 2 + QM) * HTB;
    const int pp = lane & 15, q = (lane >> 4) * 16;
#pragma unroll
    for (int mi = 0; mi < 4; ++mi) {
        int row = wm * 64 + mi * 16 + pp;
        a[mi] = *(const int32x4*)(base + row * 64 + (q ^ ((row & 3) << 4)));
    }
}

template <int QN>
__device__ inline void read_B(const char* smem, int buf, int wn, int lane, int32x4 (&bq)[2]) {
    const char* base = smem + ((buf * 2 + 1) * 2 + QN) * HTB;
    const int pp = lane & 15, q = (lane >> 4) * 16;
#pragma unroll
    for (int nj = 0; nj < 2; ++nj) {
        int row = wn * 32 + nj * 16 + pp;
        bq[nj] = *(const int32x4*)(base + row * 64 + (q ^ ((row & 3) << 4)));
    }
}

template <int QM, int QN>
__device__ inline void mfma8(int32x4 (&a)[4], int32x4 (&bq)[2], int32x4 (&acc)[2][4][2][2]) {
    __builtin_amdgcn_s_setprio(1);
#pragma unroll
    for (int mi = 0; mi < 4; ++mi)
#pragma unroll
        for (int nj = 0; nj < 2; ++nj)
            acc[QM][mi][QN][nj] = __builtin_amdgcn_mfma_i32_16x16x64_i8(
                a[mi], bq[nj], acc[QM][mi][QN][nj], 0, 0, 0);
    __builtin_amdgcn_s_setprio(0);
}

// ---------- the 8-phase 256x256 i8 GEMM (R6-proven schedule, 64 KiB LDS, 2 blk/CU) ----------
__global__ __launch_bounds__(512, 4) void w4a16_gemm_i8(
    const uint4* __restrict__ xq4, const uint4* __restrict__ wq4,
    const float* __restrict__ srow, const float* __restrict__ scales,
    const float* __restrict__ bias, float* __restrict__ out) {

    extern __shared__ __align__(16) char smem[];   // 64 KiB

    const int tid  = threadIdx.x;
    const int lane = tid & 63;
    const int wid  = tid >> 6;     // 0..7
    const int wm   = wid >> 2;     // 0..1
    const int wn   = wid & 3;      // 0..3

    // 2-D supertile mapping: XCD (bid&7) owns m-tile rows [4*xcd, 4*xcd+4).
    const int bid = blockIdx.x;
    const int xcd = bid & 7;
    const int p   = bid >> 3;          // 0..171
    int tm, tn;
    if (p < 160) { int c = p >> 4, q = p & 15; tm = xcd * 4 + (q & 3); tn = c * 4 + (q >> 2); }
    else         { int q = p - 160;            tm = xcd * 4 + (q & 3); tn = 40 + (q >> 2); }
    const int bm0 = tm * BM;
    const int bn0 = tn * BN;

    // per-thread pre-swizzled staging bases (lane l: row sub = l>>2, chunk (l&3)^((l>>2)&3))
    const int l2 = lane >> 2;
    const int csw = (lane & 3) ^ (l2 & 3);
    const uint4* gA = xq4 + (size_t)(bm0 + (wid >> 2) * 128 + (wid & 3) * 16 + l2) * KC + csw;
    const uint4* gB = wq4 + (size_t)(bn0 + (wid >> 1) * 64 + (wid & 1) * 16 + l2) * KC + csw;
    const int wo = wid * 1024;

    int32x4 acc[2][4][2][2];
#pragma unroll
    for (int qm = 0; qm < 2; ++qm)
#pragma unroll
        for (int mi = 0; mi < 4; ++mi)
#pragma unroll
            for (int qn = 0; qn < 2; ++qn)
#pragma unroll
                for (int nj = 0; nj < 2; ++nj) acc[qm][mi][qn][nj] = {0, 0, 0, 0};

    int32x4 a[4];       // current qm's A frags
    int32x4 b[2][2];    // both qn's B frags

    // prologue: tile0 -> buf0, tile1 -> buf1 (8 stages = 8 loads); VMW(4)
    // completes tile0's 4, leaves tile1's 4 in flight (= steady-state entry).
    stA(smem, gA, 0, 0, 0, wo); stB(smem, gB, 0, 0, 0, wo);
    stA(smem, gA, 0, 1, 0, wo); stB(smem, gB, 0, 1, 0, wo);
    stA(smem, gA, 1, 0, 1, wo); stB(smem, gB, 1, 0, 1, wo);
    stB(smem, gB, 1, 1, 1, wo); stA(smem, gA, 1, 1, 1, wo);
    VMW(4); SBAR0(); BAR();

    // FIFO (1 load/stage): at P4 outstanding = {t_next:4} + {t2:4} = 8 -> VMW(4)
    // completes the buf-to-be-read tile; BAR makes the drain collective.
    for (int i = 0; i < KT / 2; ++i) {
        const int t2 = 2 * i + 2, t3 = 2 * i + 3;
        // ---- P1: q(0,0) of buf0 ----
        read_A<0>(smem, 0, wm, lane, a);
        read_B<0>(smem, 0, wn, lane, b[0]);
        BAR(); mfma8<0, 0>(a, b[0], acc); BAR();
        // ---- P2: q(0,1); stage t2.A0 (buf0.A0 last read P1) ----
        stA(smem, gA, t2, 0, 0, wo);
        read_B<1>(smem, 0, wn, lane, b[1]);
        BAR(); mfma8<0, 1>(a, b[1], acc); BAR();
        // ---- P3: q(1,0); stage t2.B1 ----
        stB(smem, gB, t2, 1, 0, wo);
        read_A<1>(smem, 0, wm, lane, a);
        BAR(); mfma8<1, 0>(a, b[0], acc); BAR();
        // ---- P4: q(1,1); stage t2.B0 + t2.A1; GATE buf1 ----
        stB(smem, gB, t2, 0, 0, wo);
        stA(smem, gA, t2, 1, 0, wo);
        VMW(4); SBAR0(); BAR();
        mfma8<1, 1>(a, b[1], acc); BAR();
        // ---- P5: q(0,0) of buf1 ----
        read_A<0>(smem, 1, wm, lane, a);
        read_B<0>(smem, 1, wn, lane, b[0]);
        BAR(); mfma8<0, 0>(a, b[0], acc); BAR();
        // ---- P6: q(0,1); stage t3.A0 ----
        stA(smem, gA, t3, 0, 1, wo);
        read_B<1>(smem, 1, wn, lane, b[1]);
        BAR(); mfma8<0, 1>(a, b[1], acc); BAR();
        // ---- P7: q(1,0); stage t3.B1 ----
        stB(smem, gB, t3, 1, 1, wo);
        read_A<1>(smem, 1, wm, lane, a);
        BAR(); mfma8<1, 0>(a, b[0], acc); BAR();
        // ---- P8: q(1,1); stage t3.B0 + t3.A1; GATE buf0 ----
        stB(smem, gB, t3, 0, 1, wo);
        stA(smem, gA, t3, 1, 1, wo);
        VMW(4); SBAR0(); BAR();
        mfma8<1, 1>(a, b[1], acc); BAR();
    }
    VMW(0);   // drain wrapped trailing stages before LDS may be reused

    // ---- epilogue: out = i32_acc * srow[row] * scales[col] + bias[col] ----
    // C/D layout: col = lane&15, row = (lane>>4)*4 + rr
#pragma unroll
    for (int qm = 0; qm < 2; ++qm)
#pragma unroll
        for (int mi = 0; mi < 4; ++mi) {
            int row0 = bm0 + wm * 128 + qm * 64 + mi * 16 + (lane >> 4) * 4;
            float sr[4];
#pragma unroll
            for (int rr = 0; rr < 4; ++rr) sr[rr] = srow[row0 + rr];
#pragma unroll
            for (int qn = 0; qn < 2; ++qn)
#pragma unroll
                for (int nj = 0; nj < 2; ++nj) {
                    int col  = bn0 + wn * 64 + qn * 32 + nj * 16 + (lane & 15);
                    float sc = scales[col];
                    float bv = bias[col];
#pragma unroll
                    for (int rr = 0; rr < 4; ++rr)
                        __builtin_nontemporal_store(
                            (float)acc[qm][mi][qn][nj][rr] * (sr[rr] * sc) + bv,
                            &out[(size_t)(row0 + rr) * OUT_F + col]);
                }
        }
}

// ---------- fallback (ws too small): reg-staged bf16 128^2 with inline dequant ----------
#define FBM 128
#define FBN 128
#define FTM (M_DIM / FBM)
#define FTN (OUT_F / FBN)
#define FNWG (FTM * FTN)

__global__ __launch_bounds__(256) void w4a16_gemm_fb(
    const float* __restrict__ xf,
    const int* __restrict__ pw,
    const float* __restrict__ scales, const int* __restrict__ zps,
    const float* __restrict__ bias, float* __restrict__ out) {

    __shared__ __align__(16) __bf16 As[FBM * 64];
    __shared__ __align__(16) __bf16 Bs[FBN * 64];

    const int tid  = threadIdx.x;
    const int lane = tid & 63;
    const int wid  = tid >> 6;
    const int wm   = wid >> 1;
    const int wn   = wid & 1;

    int orig = blockIdx.x;
    int wg   = (orig & 7) * (FNWG / 8) + (orig >> 3);
    const int bm0 = (wg / FTN) * FBM;
    const int bn0 = (wg % FTN) * FBN;

    f32x4 acc[4][4];
#pragma unroll
    for (int i = 0; i < 4; ++i)
#pragma unroll
        for (int j = 0; j < 4; ++j) acc[i][j] = {0.f, 0.f, 0.f, 0.f};

    for (int kt = 0; kt < IN_F / 64; ++kt) {
#pragma unroll
        for (int i = 0; i < 4; ++i) {
            int ci  = i * 256 + tid;
            int row = ci >> 3, c8 = ci & 7;
            const float4* pp = (const float4*)(xf + (size_t)(bm0 + row) * IN_F + kt * 64 + c8 * 8);
            uint4 d = pack8_f(pp[0], pp[1]);
            *(uint4*)((char*)As + row * 128 + ((c8 * 16) ^ ((row & 7) << 4))) = d;
        }
#pragma unroll
        for (int i = 0; i < 4; ++i) {
            int ci  = i * 256 + tid;
            int row = ci >> 3, c8 = ci & 7;
            int r    = bn0 + row;
            float s  = scales[r];
            float zb = -s * (float)zps[r];
            int4 v = *(const int4*)(pw + (size_t)r * (IN_F / 2) + kt * 32 + c8 * 4);
            uint4 d = dequant8(v, s, zb);
            *(uint4*)((char*)Bs + row * 128 + ((c8 * 16) ^ ((row & 7) << 4))) = d;
        }
        __syncthreads();

#pragma unroll
        for (int kk = 0; kk < 2; ++kk) {
            short8 a[4], b[4];
#pragma unroll
            for (int mi = 0; mi < 4; ++mi) {
                int row = wm * 64 + mi * 16 + (lane & 15);
                a[mi] = *(const short8*)((const char*)As + row * 128 +
                                         ((kk * 64 + (lane >> 4) * 16) ^ ((row & 7) << 4)));
            }
#pragma unroll
            for (int ni = 0; ni < 4; ++ni) {
                int row = wn * 64 + ni * 16 + (lane & 15);
                b[ni] = *(const short8*)((const char*)Bs + row * 128 +
                                         ((kk * 64 + (lane >> 4) * 16) ^ ((row & 7) << 4)));
            }
#pragma unroll
            for (int mi = 0; mi < 4; ++mi)
#pragma unroll
                for (int ni = 0; ni < 4; ++ni)
                    acc[mi][ni] = __builtin_amdgcn_mfma_f32_16x16x32_bf16(a[mi], b[ni], acc[mi][ni], 0, 0, 0);
        }
        __syncthreads();
    }

#pragma unroll
    for (int ni = 0; ni < 4; ++ni) {
        int col  = bn0 + wn * 64 + ni * 16 + (lane & 15);
        float bv = bias[col];
#pragma unroll
        for (int mi = 0; mi < 4; ++mi) {
            int row0 = bm0 + wm * 64 + mi * 16 + (lane >> 4) * 4;
#pragma unroll
            for (int r = 0; r < 4; ++r)
                out[(size_t)(row0 + r) * OUT_F + col] = acc[mi][ni][r] + bv;
        }
    }
}

extern "C" void kernel_launch(void* const* d_in, const int* in_sizes, int n_in,
                              void* d_out, int out_size, void* d_ws, size_t ws_size,
                              hipStream_t stream) {
    const float* x      = (const float*)d_in[0];
    const int* pw       = (const int*)d_in[1];
    const float* scales = (const float*)d_in[2];
    const int* zps      = (const int*)d_in[3];
    const float* bias   = (const float*)d_in[4];
    float* out          = (float*)d_out;

    const size_t xq_bytes = (size_t)M_DIM * IN_F;        // 32 MiB i8
    const size_t sr_bytes = 65536;                       // srow f32 + pad
    const size_t wq_bytes = (size_t)OUT_F * IN_F;        // ~43 MiB i8
    const bool predeq = ws_size >= xq_bytes + sr_bytes + wq_bytes;

    if (predeq) {
        char*  xq   = (char*)d_ws;
        float* srow = (float*)((char*)d_ws + xq_bytes);
        char*  wq   = (char*)d_ws + xq_bytes + sr_bytes;
        quant_x_kernel<<<dim3(M_DIM), dim3(256), 0, stream>>>(x, xq, srow);
        deqw_i8_kernel<<<dim3(2048), dim3(256), 0, stream>>>(pw, zps, wq, OUT_F * (IN_F / 16));
        (void)hipFuncSetAttribute((const void*)w4a16_gemm_i8,
                                  hipFuncAttributeMaxDynamicSharedMemorySize, 65536);
        w4a16_gemm_i8<<<dim3(NWG), dim3(512), 65536, stream>>>(
            (const uint4*)xq, (const uint4*)wq, srow, scales, bias, out);
    } else {
        w4a16_gemm_fb<<<dim3(FNWG), dim3(256), 0, stream>>>(x, pw, scales, zps, bias, out);
    }
}

// Round 8
// 434.364 us; speedup vs baseline: 7.9171x; 7.9171x over previous
//
#include <hip/hip_runtime.h>
#include <hip/hip_bf16.h>
#include <stdint.h>

#define IN_F   4096
#define OUT_F  11008
#define M_DIM  8192          // B*S

// ---------------- 8-phase 256x256 geometry, int8 ----------------
#define BM 256
#define BN 256
#define BK 64                  // 64 i8 elems = 64 B per row per K-tile
#define TM (M_DIM / BM)        // 32
#define TN (OUT_F / BN)        // 43
#define NWG (TM * TN)          // 1376
#define KT (IN_F / BK)         // 64 K-tiles
#define KC (IN_F / 16)         // 256 16-B chunks per row
#define HTB (128 * 64)         // half-tile bytes (128 rows x 64 B) = 8 KiB

typedef __attribute__((ext_vector_type(4))) int   int32x4;
typedef __attribute__((ext_vector_type(8))) short short8;
typedef __attribute__((ext_vector_type(4))) float f32x4;

union Pack8 { __bf16 h[8]; uint4 u; };
union PackI { char c[16]; ::int4 v; };

__device__ inline uint4 pack8_f(float4 f0, float4 f1) {
    Pack8 o;
    o.h[0] = (__bf16)f0.x; o.h[1] = (__bf16)f0.y;
    o.h[2] = (__bf16)f0.z; o.h[3] = (__bf16)f0.w;
    o.h[4] = (__bf16)f1.x; o.h[5] = (__bf16)f1.y;
    o.h[6] = (__bf16)f1.z; o.h[7] = (__bf16)f1.w;
    return o.u;
}

__device__ inline uint4 dequant8(int4 v, float s, float zb) {
    Pack8 o;
    int pv[4] = {v.x, v.y, v.z, v.w};
#pragma unroll
    for (int j = 0; j < 4; ++j) {
        o.h[2 * j]     = (__bf16)fmaf((float)(pv[j] & 15), s, zb);
        o.h[2 * j + 1] = (__bf16)fmaf((float)((pv[j] >> 4) & 15), s, zb);
    }
    return o.u;
}

#define GLOAD_LDS16(g, l)                                                     \
    __builtin_amdgcn_global_load_lds(                                         \
        (const __attribute__((address_space(1))) void*)(g),                   \
        (__attribute__((address_space(3))) void*)(l), 16, 0, 0)

#define BAR()   __builtin_amdgcn_s_barrier()
#define SBAR0() __builtin_amdgcn_sched_barrier(0)
#define VMW(n)  asm volatile("s_waitcnt vmcnt(" #n ")" ::: "memory")

// ---------- preprocessing: x fp32 -> i8 with per-row absmax scale ----------
__global__ __launch_bounds__(256) void quant_x_kernel(const float* __restrict__ x,
        char* __restrict__ xq, float* __restrict__ srow) {
    const int row = blockIdx.x;
    const int t   = threadIdx.x;
    const float4* xr = (const float4*)(x + (size_t)row * IN_F) + t * 4;
    float4 v[4];
    float am = 0.f;
#pragma unroll
    for (int j = 0; j < 4; ++j) {
        v[j] = xr[j];
        am = fmaxf(am, fmaxf(fmaxf(fabsf(v[j].x), fabsf(v[j].y)),
                             fmaxf(fabsf(v[j].z), fabsf(v[j].w))));
    }
#pragma unroll
    for (int off = 32; off; off >>= 1) am = fmaxf(am, __shfl_xor(am, off, 64));
    __shared__ float wm4[4];
    if ((t & 63) == 0) wm4[t >> 6] = am;
    __syncthreads();
    am = fmaxf(fmaxf(wm4[0], wm4[1]), fmaxf(wm4[2], wm4[3]));
    const float qs = am > 0.f ? 127.f / am : 0.f;
    if (t == 0) srow[row] = am > 0.f ? am * (1.f / 127.f) : 0.f;
    PackI o;
#pragma unroll
    for (int j = 0; j < 4; ++j) {
        const float* f = (const float*)&v[j];
#pragma unroll
        for (int e = 0; e < 4; ++e) {
            float q = rintf(f[e] * qs);
            q = fminf(127.f, fmaxf(-127.f, q));
            o.c[j * 4 + e] = (char)(int)q;
        }
    }
    ((::int4*)(xq + (size_t)row * IN_F))[t] = o.v;
}

// ---------- preprocessing: packed int4 W -> i8 (q - zp, EXACT) ----------
__global__ void deqw_i8_kernel(const int* __restrict__ pw, const int* __restrict__ zps,
                               char* __restrict__ wq, int nChunks) {
    int stride = gridDim.x * blockDim.x;
    for (int c = blockIdx.x * blockDim.x + threadIdx.x; c < nChunks; c += stride) {
        int row = c >> 8;          // 256 16-B chunks per row
        int cc  = c & 255;
        int zp  = zps[row];
        const ::int4* p = (const ::int4*)(pw + (size_t)row * (IN_F / 2) + cc * 8);
        ::int4 v0 = p[0], v1 = p[1];
        int pv[8] = {v0.x, v0.y, v0.z, v0.w, v1.x, v1.y, v1.z, v1.w};
        PackI o;
#pragma unroll
        for (int j = 0; j < 8; ++j) {
            o.c[2 * j]     = (char)((pv[j] & 15) - zp);
            o.c[2 * j + 1] = (char)(((pv[j] >> 4) & 15) - zp);
        }
        ((::int4*)wq)[c] = o.v;
    }
}

// ---------- 8-phase helpers (i8: 1 gload_lds per wave per half-tile) ----------
// LDS half-tile: [128 rows][64 B]. Bank-conflict-free swizzle for 64-B rows:
// 16-B slot s of row r holds global chunk s ^ ((r>>1)&3)  (bank group
// g = 4*(r&1) + s'  takes all 8 values over 8 consecutive rows -> 2 lanes/bank).
// gload_lds writes linearly (lane l -> row wid*16 + (l>>2), slot l&3), so the
// pre-swizzled source chunk is (l&3) ^ ((l>>3)&3).
__device__ inline void stA(char* smem, const uint4* gA, int t, int h, int buf, int wo) {
    GLOAD_LDS16(gA + (size_t)h * 64 * KC + (t & (KT - 1)) * 4,
                smem + ((buf * 2 + 0) * 2 + h) * HTB + wo);
}
__device__ inline void stB(char* smem, const uint4* gB, int t, int h, int buf, int wo) {
    GLOAD_LDS16(gB + (size_t)h * 32 * KC + (t & (KT - 1)) * 4,
                smem + ((buf * 2 + 1) * 2 + h) * HTB + wo);
}

template <int QM>
__device__ inline void read_A(const char* smem, int buf, int wm, int lane, int32x4 (&a)[4]) {
    const char* base = smem + ((buf * 2 + 0) * 2 + QM) * HTB;
    const int pp = lane & 15, q = (lane >> 4) * 16;
#pragma unroll
    for (int mi = 0; mi < 4; ++mi) {
        int row = wm * 64 + mi * 16 + pp;
        a[mi] = *(const int32x4*)(base + row * 64 + (q ^ (((row >> 1) & 3) << 4)));
    }
}

template <int QN>
__device__ inline void read_B(const char* smem, int buf, int wn, int lane, int32x4 (&bq)[2]) {
    const char* base = smem + ((buf * 2 + 1) * 2 + QN) * HTB;
    const int pp = lane & 15, q = (lane >> 4) * 16;
#pragma unroll
    for (int nj = 0; nj < 2; ++nj) {
        int row = wn * 32 + nj * 16 + pp;
        bq[nj] = *(const int32x4*)(base + row * 64 + (q ^ (((row >> 1) & 3) << 4)));
    }
}

template <int QM, int QN>
__device__ inline void mfma8(int32x4 (&a)[4], int32x4 (&bq)[2], int32x4 (&acc)[2][4][2][2]) {
    __builtin_amdgcn_s_setprio(1);
#pragma unroll
    for (int mi = 0; mi < 4; ++mi)
#pragma unroll
        for (int nj = 0; nj < 2; ++nj)
            acc[QM][mi][QN][nj] = __builtin_amdgcn_mfma_i32_16x16x64_i8(
                a[mi], bq[nj], acc[QM][mi][QN][nj], 0, 0, 0);
    __builtin_amdgcn_s_setprio(0);
}

// ---------- the 8-phase 256x256 i8 GEMM ----------
// launch_bounds (512,2): R7's (512,4) capped VGPR at 64 -> full acc spill ->
// 16 GB scratch traffic. (512,2) is R6's proven no-spill setting.
__global__ __launch_bounds__(512, 2) void w4a16_gemm_i8(
    const uint4* __restrict__ xq4, const uint4* __restrict__ wq4,
    const float* __restrict__ srow, const float* __restrict__ scales,
    const float* __restrict__ bias, float* __restrict__ out) {

    extern __shared__ __align__(16) char smem[];   // 64 KiB

    const int tid  = threadIdx.x;
    const int lane = tid & 63;
    const int wid  = tid >> 6;     // 0..7
    const int wm   = wid >> 2;     // 0..1
    const int wn   = wid & 3;      // 0..3

    // 2-D supertile mapping: XCD (bid&7) owns m-tile rows [4*xcd, 4*xcd+4).
    const int bid = blockIdx.x;
    const int xcd = bid & 7;
    const int p   = bid >> 3;          // 0..171
    int tm, tn;
    if (p < 160) { int c = p >> 4, q = p & 15; tm = xcd * 4 + (q & 3); tn = c * 4 + (q >> 2); }
    else         { int q = p - 160;            tm = xcd * 4 + (q & 3); tn = 40 + (q >> 2); }
    const int bm0 = tm * BM;
    const int bn0 = tn * BN;

    // per-thread pre-swizzled staging bases (lane l: sub-row l>>2, chunk (l&3)^((l>>3)&3))
    const int l2  = lane >> 2;
    const int csw = (lane & 3) ^ ((lane >> 3) & 3);
    const uint4* gA = xq4 + (size_t)(bm0 + (wid >> 2) * 128 + (wid & 3) * 16 + l2) * KC + csw;
    const uint4* gB = wq4 + (size_t)(bn0 + (wid >> 1) * 64 + (wid & 1) * 16 + l2) * KC + csw;
    const int wo = wid * 1024;

    int32x4 acc[2][4][2][2];
#pragma unroll
    for (int qm = 0; qm < 2; ++qm)
#pragma unroll
        for (int mi = 0; mi < 4; ++mi)
#pragma unroll
            for (int qn = 0; qn < 2; ++qn)
#pragma unroll
                for (int nj = 0; nj < 2; ++nj) acc[qm][mi][qn][nj] = {0, 0, 0, 0};

    int32x4 a[4];       // current qm's A frags
    int32x4 b[2][2];    // both qn's B frags

    // prologue: tile0 -> buf0, tile1 -> buf1 (8 stages = 8 loads); VMW(4)
    // completes tile0's 4, leaves tile1's 4 in flight (= steady-state entry).
    stA(smem, gA, 0, 0, 0, wo); stB(smem, gB, 0, 0, 0, wo);
    stA(smem, gA, 0, 1, 0, wo); stB(smem, gB, 0, 1, 0, wo);
    stA(smem, gA, 1, 0, 1, wo); stB(smem, gB, 1, 0, 1, wo);
    stB(smem, gB, 1, 1, 1, wo); stA(smem, gA, 1, 1, 1, wo);
    VMW(4); SBAR0(); BAR();

    // FIFO (1 load/stage): at P4/P8 outstanding = 8 -> VMW(4) completes the
    // tile the next phases read; BAR after VMW makes the drain collective.
    for (int i = 0; i < KT / 2; ++i) {
        const int t2 = 2 * i + 2, t3 = 2 * i + 3;
        // ---- P1: q(0,0) of buf0 ----
        read_A<0>(smem, 0, wm, lane, a);
        read_B<0>(smem, 0, wn, lane, b[0]);
        BAR(); mfma8<0, 0>(a, b[0], acc); BAR();
        // ---- P2: q(0,1); stage t2.A0 (buf0.A0 last read P1) ----
        stA(smem, gA, t2, 0, 0, wo);
        read_B<1>(smem, 0, wn, lane, b[1]);
        BAR(); mfma8<0, 1>(a, b[1], acc); BAR();
        // ---- P3: q(1,0); stage t2.B1 ----
        stB(smem, gB, t2, 1, 0, wo);
        read_A<1>(smem, 0, wm, lane, a);
        BAR(); mfma8<1, 0>(a, b[0], acc); BAR();
        // ---- P4: q(1,1); stage t2.B0 + t2.A1; GATE buf1 ----
        stB(smem, gB, t2, 0, 0, wo);
        stA(smem, gA, t2, 1, 0, wo);
        VMW(4); SBAR0(); BAR();
        mfma8<1, 1>(a, b[1], acc); BAR();
        // ---- P5: q(0,0) of buf1 ----
        read_A<0>(smem, 1, wm, lane, a);
        read_B<0>(smem, 1, wn, lane, b[0]);
        BAR(); mfma8<0, 0>(a, b[0], acc); BAR();
        // ---- P6: q(0,1); stage t3.A0 ----
        stA(smem, gA, t3, 0, 1, wo);
        read_B<1>(smem, 1, wn, lane, b[1]);
        BAR(); mfma8<0, 1>(a, b[1], acc); BAR();
        // ---- P7: q(1,0); stage t3.B1 ----
        stB(smem, gB, t3, 1, 1, wo);
        read_A<1>(smem, 1, wm, lane, a);
        BAR(); mfma8<1, 0>(a, b[0], acc); BAR();
        // ---- P8: q(1,1); stage t3.B0 + t3.A1; GATE buf0 ----
        stB(smem, gB, t3, 0, 1, wo);
        stA(smem, gA, t3, 1, 1, wo);
        VMW(4); SBAR0(); BAR();
        mfma8<1, 1>(a, b[1], acc); BAR();
    }
    VMW(0);   // drain wrapped trailing stages before LDS may be reused

    // ---- epilogue: out = i32_acc * srow[row] * scales[col] + bias[col] ----
    // C/D layout: col = lane&15, row = (lane>>4)*4 + rr
#pragma unroll
    for (int qm = 0; qm < 2; ++qm)
#pragma unroll
        for (int mi = 0; mi < 4; ++mi) {
            int row0 = bm0 + wm * 128 + qm * 64 + mi * 16 + (lane >> 4) * 4;
            float sr[4];
#pragma unroll
            for (int rr = 0; rr < 4; ++rr) sr[rr] = srow[row0 + rr];
#pragma unroll
            for (int qn = 0; qn < 2; ++qn)
#pragma unroll
                for (int nj = 0; nj < 2; ++nj) {
                    int col  = bn0 + wn * 64 + qn * 32 + nj * 16 + (lane & 15);
                    float sc = scales[col];
                    float bv = bias[col];
#pragma unroll
                    for (int rr = 0; rr < 4; ++rr)
                        __builtin_nontemporal_store(
                            (float)acc[qm][mi][qn][nj][rr] * (sr[rr] * sc) + bv,
                            &out[(size_t)(row0 + rr) * OUT_F + col]);
                }
        }
}

// ---------- fallback (ws too small): reg-staged bf16 128^2 with inline dequant ----------
#define FBM 128
#define FBN 128
#define FTM (M_DIM / FBM)
#define FTN (OUT_F / FBN)
#define FNWG (FTM * FTN)

__global__ __launch_bounds__(256) void w4a16_gemm_fb(
    const float* __restrict__ xf,
    const int* __restrict__ pw,
    const float* __restrict__ scales, const int* __restrict__ zps,
    const float* __restrict__ bias, float* __restrict__ out) {

    __shared__ __align__(16) __bf16 As[FBM * 64];
    __shared__ __align__(16) __bf16 Bs[FBN * 64];

    const int tid  = threadIdx.x;
    const int lane = tid & 63;
    const int wid  = tid >> 6;
    const int wm   = wid >> 1;
    const int wn   = wid & 1;

    int orig = blockIdx.x;
    int wg   = (orig & 7) * (FNWG / 8) + (orig >> 3);
    const int bm0 = (wg / FTN) * FBM;
    const int bn0 = (wg % FTN) * FBN;

    f32x4 acc[4][4];
#pragma unroll
    for (int i = 0; i < 4; ++i)
#pragma unroll
        for (int j = 0; j < 4; ++j) acc[i][j] = {0.f, 0.f, 0.f, 0.f};

    for (int kt = 0; kt < IN_F / 64; ++kt) {
#pragma unroll
        for (int i = 0; i < 4; ++i) {
            int ci  = i * 256 + tid;
            int row = ci >> 3, c8 = ci & 7;
            const float4* pp = (const float4*)(xf + (size_t)(bm0 + row) * IN_F + kt * 64 + c8 * 8);
            uint4 d = pack8_f(pp[0], pp[1]);
            *(uint4*)((char*)As + row * 128 + ((c8 * 16) ^ ((row & 7) << 4))) = d;
        }
#pragma unroll
        for (int i = 0; i < 4; ++i) {
            int ci  = i * 256 + tid;
            int row = ci >> 3, c8 = ci & 7;
            int r    = bn0 + row;
            float s  = scales[r];
            float zb = -s * (float)zps[r];
            int4 v = *(const int4*)(pw + (size_t)r * (IN_F / 2) + kt * 32 + c8 * 4);
            uint4 d = dequant8(v, s, zb);
            *(uint4*)((char*)Bs + row * 128 + ((c8 * 16) ^ ((row & 7) << 4))) = d;
        }
        __syncthreads();

#pragma unroll
        for (int kk = 0; kk < 2; ++kk) {
            short8 a[4], b[4];
#pragma unroll
            for (int mi = 0; mi < 4; ++mi) {
                int row = wm * 64 + mi * 16 + (lane & 15);
                a[mi] = *(const short8*)((const char*)As + row * 128 +
                                         ((kk * 64 + (lane >> 4) * 16) ^ ((row & 7) << 4)));
            }
#pragma unroll
            for (int ni = 0; ni < 4; ++ni) {
                int row = wn * 64 + ni * 16 + (lane & 15);
                b[ni] = *(const short8*)((const char*)Bs + row * 128 +
                                         ((kk * 64 + (lane >> 4) * 16) ^ ((row & 7) << 4)));
            }
#pragma unroll
            for (int mi = 0; mi < 4; ++mi)
#pragma unroll
                for (int ni = 0; ni < 4; ++ni)
                    acc[mi][ni] = __builtin_amdgcn_mfma_f32_16x16x32_bf16(a[mi], b[ni], acc[mi][ni], 0, 0, 0);
        }
        __syncthreads();
    }

#pragma unroll
    for (int ni = 0; ni < 4; ++ni) {
        int col  = bn0 + wn * 64 + ni * 16 + (lane & 15);
        float bv = bias[col];
#pragma unroll
        for (int mi = 0; mi < 4; ++mi) {
            int row0 = bm0 + wm * 64 + mi * 16 + (lane >> 4) * 4;
#pragma unroll
            for (int r = 0; r < 4; ++r)
                out[(size_t)(row0 + r) * OUT_F + col] = acc[mi][ni][r] + bv;
        }
    }
}

extern "C" void kernel_launch(void* const* d_in, const int* in_sizes, int n_in,
                              void* d_out, int out_size, void* d_ws, size_t ws_size,
                              hipStream_t stream) {
    const float* x      = (const float*)d_in[0];
    const int* pw       = (const int*)d_in[1];
    const float* scales = (const float*)d_in[2];
    const int* zps      = (const int*)d_in[3];
    const float* bias   = (const float*)d_in[4];
    float* out          = (float*)d_out;

    const size_t xq_bytes = (size_t)M_DIM * IN_F;        // 32 MiB i8
    const size_t sr_bytes = 65536;                       // srow f32 + pad
    const size_t wq_bytes = (size_t)OUT_F * IN_F;        // ~43 MiB i8
    const bool predeq = ws_size >= xq_bytes + sr_bytes + wq_bytes;

    if (predeq) {
        char*  xq   = (char*)d_ws;
        float* srow = (float*)((char*)d_ws + xq_bytes);
        char*  wq   = (char*)d_ws + xq_bytes + sr_bytes;
        quant_x_kernel<<<dim3(M_DIM), dim3(256), 0, stream>>>(x, xq, srow);
        deqw_i8_kernel<<<dim3(2048), dim3(256), 0, stream>>>(pw, zps, wq, OUT_F * (IN_F / 16));
        (void)hipFuncSetAttribute((const void*)w4a16_gemm_i8,
                                  hipFuncAttributeMaxDynamicSharedMemorySize, 65536);
        w4a16_gemm_i8<<<dim3(NWG), dim3(512), 65536, stream>>>(
            (const uint4*)xq, (const uint4*)wq, srow, scales, bias, out);
    } else {
        w4a16_gemm_fb<<<dim3(FNWG), dim3(256), 0, stream>>>(x, pw, scales, zps, bias, out);
    }
}